// Round 1
// 147.761 us; speedup vs baseline: 1.0581x; 1.0581x over previous
//
#include <hip/hip_runtime.h>
#include <cstdint>

#define LL 2048
#define HH 16
#define DD 64
#define LSTR 1024      // H*D
#define EPSF 1e-6f
#define PAD 72         // ushorts per LDS row: 144 B = 16B-aligned, 2-way (free) on b128 frags

typedef __bf16 bf16x8 __attribute__((ext_vector_type(8)));
typedef float floatx4 __attribute__((ext_vector_type(4)));
typedef unsigned short ushortx8 __attribute__((ext_vector_type(8)));
typedef unsigned short ushortx4 __attribute__((ext_vector_type(4)));
typedef unsigned short ushortx2 __attribute__((ext_vector_type(2)));

static __device__ __forceinline__ float fmap(float x){ return x > 0.f ? x + 1.f : __expf(x); }
static __device__ __forceinline__ unsigned short f2bf(float f){
    unsigned u = __builtin_bit_cast(unsigned, f);
    u += 0x7fffu + ((u >> 16) & 1u);
    return (unsigned short)(u >> 16);
}
static __device__ __forceinline__ float bf2f(unsigned short s){
    unsigned u = ((unsigned)s) << 16;
    return __builtin_bit_cast(float, u);
}
static __device__ __forceinline__ bf16x8 ldf(const unsigned short* p){
    return __builtin_bit_cast(bf16x8, *(const ushortx8*)p);
}
static __device__ __forceinline__ float4 fmap4(float4 a){
    return float4{fmap(a.x), fmap(a.y), fmap(a.z), fmap(a.w)};
}

// store rows r, r+1 of an [s][d]-layout tile (bf16), optional feature map
template<bool MAP>
static __device__ __forceinline__ void st_sd(unsigned short* base, int r, int c, float4 a, float4 b){
    if (MAP) {
        *(ushortx4*)(base + r*PAD + c)     = ushortx4{ f2bf(fmap(a.x)), f2bf(fmap(a.y)), f2bf(fmap(a.z)), f2bf(fmap(a.w)) };
        *(ushortx4*)(base + (r+1)*PAD + c) = ushortx4{ f2bf(fmap(b.x)), f2bf(fmap(b.y)), f2bf(fmap(b.z)), f2bf(fmap(b.w)) };
    } else {
        *(ushortx4*)(base + r*PAD + c)     = ushortx4{ f2bf(a.x), f2bf(a.y), f2bf(a.z), f2bf(a.w) };
        *(ushortx4*)(base + (r+1)*PAD + c) = ushortx4{ f2bf(b.x), f2bf(b.y), f2bf(b.z), f2bf(b.w) };
    }
}
// transposed store into a [d][s]- or [m][s]-layout tile (bf16), optional feature map
template<bool MAP>
static __device__ __forceinline__ void st_tr(unsigned short* base, int r, int c, float4 a, float4 b){
    float aa[4] = {a.x, a.y, a.z, a.w}, bb[4] = {b.x, b.y, b.z, b.w};
#pragma unroll
    for (int e = 0; e < 4; ++e) {
        float x0 = MAP ? fmap(aa[e]) : aa[e];
        float x1 = MAP ? fmap(bb[e]) : bb[e];
        *(ushortx2*)(base + (c+e)*PAD + r) = ushortx2{ f2bf(x0), f2bf(x1) };
    }
}

// ---------------- kA: per-oct (256-row) KV sums (fp32 [m][d]) + K colsums ----------------
__global__ __launch_bounds__(256) void kA(const float* __restrict__ kp, const float* __restrict__ vp,
                                          float* __restrict__ qkv, float* __restrict__ ksq)
{
    __shared__ __align__(16) unsigned short kft[2][DD*PAD]; // kf^T [d][s]
    __shared__ __align__(16) unsigned short vtt[2][DD*PAD]; // v^T  [m][s]
    const int blk = blockIdx.x;                 // bh*8 + oct
    const int bh = blk >> 3, oct = blk & 7, b = bh >> 4, h = bh & 15;
    const int t = threadIdx.x;
    const int w = t >> 6, lane = t & 63, quad = lane >> 4, lr = lane & 15;
    const int m0 = 16*w;

    floatx4 acc[4];
#pragma unroll
    for (int dt = 0; dt < 4; ++dt) acc[dt] = floatx4{0.f,0.f,0.f,0.f};
    float ksa = 0.f;

    const int64_t gb0 = ((int64_t)(b*LL + oct*256)*HH + h)*DD;
    // prologue: stage sub-chunk 0
#pragma unroll
    for (int ii = 0; ii < 2; ++ii) {
        int flat = t + 256*ii;
        int l0s = (flat >> 4) * 2, col4 = (flat & 15) << 2;
        const float* gk = kp + gb0 + (int64_t)l0s*LSTR + col4;
        const float* gv = vp + gb0 + (int64_t)l0s*LSTR + col4;
        float4 ka = *(const float4*)gk, kb = *(const float4*)(gk + LSTR);
        float4 va = *(const float4*)gv, vb = *(const float4*)(gv + LSTR);
        st_tr<true >(kft[0], l0s, col4, ka, kb);
        st_tr<false>(vtt[0], l0s, col4, va, vb);
    }
    __syncthreads();

#pragma unroll
    for (int sc = 0; sc < 4; ++sc) {
        const int p = sc & 1;
        float4 ka[2], kb[2], va[2], vb[2];
        if (sc < 3) {
            const int64_t gb = gb0 + (int64_t)(sc+1)*DD*LSTR;
#pragma unroll
            for (int ii = 0; ii < 2; ++ii) {
                int flat = t + 256*ii;
                int l0s = (flat >> 4) * 2, col4 = (flat & 15) << 2;
                const float* gk = kp + gb + (int64_t)l0s*LSTR + col4;
                const float* gv = vp + gb + (int64_t)l0s*LSTR + col4;
                ka[ii] = *(const float4*)gk; kb[ii] = *(const float4*)(gk + LSTR);
                va[ii] = *(const float4*)gv; vb[ii] = *(const float4*)(gv + LSTR);
            }
        }
        // accumulate KV^T[m][d] over this sub-chunk
#pragma unroll
        for (int kk = 0; kk < 2; ++kk) {
            bf16x8 a = ldf(vtt[p] + (m0+lr)*PAD + kk*32 + quad*8);
#pragma unroll
            for (int dt = 0; dt < 4; ++dt) {
                bf16x8 bbf = ldf(kft[p] + (dt*16+lr)*PAD + kk*32 + quad*8);
                acc[dt] = __builtin_amdgcn_mfma_f32_16x16x32_bf16(a, bbf, acc[dt], 0, 0, 0);
            }
        }
        if (t < DD) {
#pragma unroll
            for (int jj = 0; jj < 8; ++jj) {
                ushortx8 u = *(const ushortx8*)(kft[p] + t*PAD + jj*8);
#pragma unroll
                for (int e = 0; e < 8; ++e) ksa += bf2f(u[e]);
            }
        }
        if (sc < 3) {
#pragma unroll
            for (int ii = 0; ii < 2; ++ii) {
                int flat = t + 256*ii;
                int l0s = (flat >> 4) * 2, col4 = (flat & 15) << 2;
                st_tr<true >(kft[p^1], l0s, col4, ka[ii], kb[ii]);
                st_tr<false>(vtt[p^1], l0s, col4, va[ii], vb[ii]);
            }
        }
        __syncthreads();
    }

    float* qo = qkv + (int64_t)blk*4096;        // [m][d] fp32
#pragma unroll
    for (int dt = 0; dt < 4; ++dt)
#pragma unroll
        for (int r = 0; r < 4; ++r)
            qo[(m0 + quad*4 + r)*DD + dt*16 + lr] = acc[dt][r];
    if (t < DD) ksq[(int64_t)blk*DD + t] = ksa;
}

// ---------------- kM: causal chunk recurrence over one quarter (8 chunks), S in fp32 regs ----------------
__global__ __launch_bounds__(512) void kM(const float* __restrict__ qp, const float* __restrict__ kp,
                                          const float* __restrict__ vp,
                                          const float* __restrict__ qkv, const float* __restrict__ ksq,
                                          float* __restrict__ outp)
{
    __shared__ __align__(16) unsigned short qf [DD*PAD];   // qf [l][d]
    __shared__ __align__(16) unsigned short kfx[DD*PAD];   // kf [s][d]
    __shared__ __align__(16) unsigned short kft[DD*PAD];   // kf^T [d][s]
    __shared__ __align__(16) unsigned short vtt[DD*PAD];   // v^T [m][s]
    __shared__ __align__(16) unsigned short sld[DD*PAD];   // S   [m][d] bf16
    __shared__ __align__(16) unsigned short sct[DD*PAD];   // masked scores [l][s]
    __shared__ __align__(16) unsigned short kpx[16*PAD];   // row0 = ksum prefix (bf16), rows 1..15 = 0
    __shared__ float ksum[DD];
    __shared__ float zp2[2][DD];

    const int bid = blockIdx.x;
    const int bh = bid & 63, qtr = bid >> 6, b = bh >> 4, h = bh & 15;
    const int t = threadIdx.x;
    const int w = t >> 6, lane = t & 63, quad = lane >> 4, lr = lane & 15;
    const int wi = w >> 1, wj = w & 1;          // l/m tile (16 rows), s/m/d half
    const int l0 = 16*wi;
    const int l0s = (t >> 4) * 2, col4 = (t & 15) << 2;   // staging slots (512 threads)

    const int64_t bhb = ((int64_t)b*LL*HH + h)*DD;
    const int cg0 = qtr*8;

    // ---- prologue ----
    if (t < 135) *(ushortx8*)(kpx + PAD + t*8) = ushortx8{0,0,0,0,0,0,0,0};
    const int no = 2*qtr;                       // octs before this quarter
    if (t < DD) {
        float s = 0.f;
        for (int o = 0; o < no; ++o) s += ksq[((int64_t)bh*8 + o)*DD + t];
        ksum[t] = s;
        kpx[t] = f2bf(s);
    }
    floatx4 S_acc[2];
    S_acc[0] = floatx4{0.f,0.f,0.f,0.f};
    S_acc[1] = floatx4{0.f,0.f,0.f,0.f};
    for (int o = 0; o < no; ++o) {
        const float* qo = qkv + ((int64_t)bh*8 + o)*4096;
#pragma unroll
        for (int dtl = 0; dtl < 2; ++dtl)
#pragma unroll
            for (int r = 0; r < 4; ++r)
                S_acc[dtl][r] += qo[(l0 + quad*4 + r)*DD + 32*wj + dtl*16 + lr];
    }
#pragma unroll
    for (int dtl = 0; dtl < 2; ++dtl)
#pragma unroll
        for (int r = 0; r < 4; ++r)
            sld[(l0 + quad*4 + r)*PAD + 32*wj + dtl*16 + lr] = f2bf(S_acc[dtl][r]);

    // stage chunk 0 (all four tiles)
    {
        const int64_t gb = bhb + (int64_t)cg0*DD*LSTR;
        const float* gq = qp + gb + (int64_t)l0s*LSTR + col4;
        const float* gk = kp + gb + (int64_t)l0s*LSTR + col4;
        const float* gv = vp + gb + (int64_t)l0s*LSTR + col4;
        float4 q0 = *(const float4*)gq, q1 = *(const float4*)(gq + LSTR);
        float4 k0 = *(const float4*)gk, k1 = *(const float4*)(gk + LSTR);
        float4 v0 = *(const float4*)gv, v1 = *(const float4*)(gv + LSTR);
        st_sd<true >(qf , l0s, col4, q0, q1);
        st_sd<true >(kfx, l0s, col4, k0, k1);
        st_tr<true >(kft, l0s, col4, k0, k1);
        st_tr<false>(vtt, l0s, col4, v0, v1);
    }
    __syncthreads();                            // barrier A (chunk 0)

    float4 lk0 = float4{0,0,0,0}, lk1 = float4{0,0,0,0};
    float4 lv0 = float4{0,0,0,0}, lv1 = float4{0,0,0,0};

#pragma unroll 2
    for (int c = 0; c < 8; ++c) {
        const int cg = cg0 + c;
        // [1] issue global loads for chunk c+1
        float4 nq0, nq1, nk0, nk1, nv0, nv1;
        if (c < 7) {
            const int64_t gb = bhb + (int64_t)(cg+1)*DD*LSTR;
            const float* gq = qp + gb + (int64_t)l0s*LSTR + col4;
            const float* gk = kp + gb + (int64_t)l0s*LSTR + col4;
            const float* gv = vp + gb + (int64_t)l0s*LSTR + col4;
            nq0 = *(const float4*)gq; nq1 = *(const float4*)(gq + LSTR);
            nk0 = *(const float4*)gk; nk1 = *(const float4*)(gk + LSTR);
            nv0 = *(const float4*)gv; nv1 = *(const float4*)(gv + LSTR);
        }
        // [2.5] write kft/vtt for THIS chunk from carried regs (readers are post-B)
        if (c > 0) {
            st_tr<false>(kft, l0s, col4, lk0, lk1);   // lk already fmapped
            st_tr<false>(vtt, l0s, col4, lv0, lv1);
        }
        // [2] frag reads (qf chunk c; S from previous state)
        bf16x8 aq0 = ldf(qf + (l0+lr)*PAD + quad*8);
        bf16x8 aq1 = ldf(qf + (l0+lr)*PAD + 32 + quad*8);
        bf16x8 bsf[2][2];
#pragma unroll
        for (int kk = 0; kk < 2; ++kk)
#pragma unroll
            for (int mt = 0; mt < 2; ++mt)
                bsf[kk][mt] = ldf(sld + ((2*wj+mt)*16+lr)*PAD + kk*32 + quad*8);
        // [3] GEMM1: scores for this wave's s-half (+ prefix-z tile on wj==0)
        floatx4 s0 = floatx4{0.f,0.f,0.f,0.f}, s1 = floatx4{0.f,0.f,0.f,0.f}, sp = floatx4{0.f,0.f,0.f,0.f};
#pragma unroll
        for (int kk = 0; kk < 2; ++kk) {
            bf16x8 aqk = kk ? aq1 : aq0;
            bf16x8 b0 = ldf(kfx + ((2*wj+0)*16+lr)*PAD + kk*32 + quad*8);
            bf16x8 b1 = ldf(kfx + ((2*wj+1)*16+lr)*PAD + kk*32 + quad*8);
            s0 = __builtin_amdgcn_mfma_f32_16x16x32_bf16(aqk, b0, s0, 0, 0, 0);
            s1 = __builtin_amdgcn_mfma_f32_16x16x32_bf16(aqk, b1, s1, 0, 0, 0);
            if (wj == 0) {
                bf16x8 bp = ldf(kpx + lr*PAD + kk*32 + quad*8);
                sp = __builtin_amdgcn_mfma_f32_16x16x32_bf16(aqk, bp, sp, 0, 0, 0);
            }
        }
        // [4] causal mask + overlay to sct + z partial
        float zpv[4];
#pragma unroll
        for (int r = 0; r < 4; ++r) zpv[r] = (wj == 0 && lr == 0) ? sp[r] : 0.f;
#pragma unroll
        for (int tt = 0; tt < 2; ++tt) {
            int colb = (2*wj+tt)*16 + lr;
            floatx4 sv = tt ? s1 : s0;
#pragma unroll
            for (int r = 0; r < 4; ++r) {
                int row = l0 + quad*4 + r;
                float val = (colb <= row) ? sv[r] : 0.f;
                zpv[r] += val;
                sct[row*PAD + colb] = f2bf(val);
            }
        }
#pragma unroll
        for (int m = 1; m < 16; m <<= 1)
#pragma unroll
            for (int r = 0; r < 4; ++r) zpv[r] += __shfl_xor(zpv[r], m, 64);
        if (lr == 0) {
#pragma unroll
            for (int r = 0; r < 4; ++r) zp2[wj][l0 + quad*4 + r] = zpv[r];
        }
        __syncthreads();                        // barrier B
        // [5] ksum += colsum(kf chunk c); refresh kpx row 0 (used from chunk c+1)
        if (t < DD) {
            float s = ksum[t];
#pragma unroll
            for (int jj = 0; jj < 8; ++jj) {
                ushortx8 u = *(const ushortx8*)(kft + t*PAD + jj*8);
#pragma unroll
                for (int e = 0; e < 8; ++e) s += bf2f(u[e]);
            }
            ksum[t] = s;
            kpx[t] = f2bf(s);
        }
        // [7] GEMM2: out = maskedP * v + qf * S
        floatx4 oa0 = floatx4{0.f,0.f,0.f,0.f}, oa1 = floatx4{0.f,0.f,0.f,0.f};
#pragma unroll
        for (int kk = 0; kk < 2; ++kk) {
            bf16x8 a2  = ldf(sct + (l0+lr)*PAD + kk*32 + quad*8);
            bf16x8 bv0 = ldf(vtt + ((2*wj+0)*16+lr)*PAD + kk*32 + quad*8);
            bf16x8 bv1 = ldf(vtt + ((2*wj+1)*16+lr)*PAD + kk*32 + quad*8);
            oa0 = __builtin_amdgcn_mfma_f32_16x16x32_bf16(a2, bv0, oa0, 0, 0, 0);
            oa1 = __builtin_amdgcn_mfma_f32_16x16x32_bf16(a2, bv1, oa1, 0, 0, 0);
        }
        oa0 = __builtin_amdgcn_mfma_f32_16x16x32_bf16(aq0, bsf[0][0], oa0, 0, 0, 0);
        oa0 = __builtin_amdgcn_mfma_f32_16x16x32_bf16(aq1, bsf[1][0], oa0, 0, 0, 0);
        oa1 = __builtin_amdgcn_mfma_f32_16x16x32_bf16(aq0, bsf[0][1], oa1, 0, 0, 0);
        oa1 = __builtin_amdgcn_mfma_f32_16x16x32_bf16(aq1, bsf[1][1], oa1, 0, 0, 0);
        // [8] normalize + store
        {
            const int64_t ob = bhb + (int64_t)cg*DD*LSTR;
#pragma unroll
            for (int r = 0; r < 4; ++r) {
                int row = l0 + quad*4 + r;
                float rz = 1.f / (zp2[0][row] + zp2[1][row] + EPSF);
                outp[ob + (int64_t)row*LSTR + (2*wj+0)*16 + lr] = oa0[r] * rz;
                outp[ob + (int64_t)row*LSTR + (2*wj+1)*16 + lr] = oa1[r] * rz;
            }
        }
        // [9] S += kf^T v for chunk c (fp32 accumulators), refresh sld (read from chunk c+1)
#pragma unroll
        for (int kk = 0; kk < 2; ++kk) {
            bf16x8 av = ldf(vtt + (l0+lr)*PAD + kk*32 + quad*8);
#pragma unroll
            for (int dtl = 0; dtl < 2; ++dtl) {
                bf16x8 bk = ldf(kft + ((2*wj+dtl)*16+lr)*PAD + kk*32 + quad*8);
                S_acc[dtl] = __builtin_amdgcn_mfma_f32_16x16x32_bf16(av, bk, S_acc[dtl], 0, 0, 0);
            }
        }
#pragma unroll
        for (int dtl = 0; dtl < 2; ++dtl)
#pragma unroll
            for (int r = 0; r < 4; ++r)
                sld[(l0 + quad*4 + r)*PAD + 32*wj + dtl*16 + lr] = f2bf(S_acc[dtl][r]);
        // [10] stage qf/kfx for chunk c+1; carry fmapped k and raw v for its kft/vtt
        if (c < 7) {
            float4 fk0 = fmap4(nk0), fk1 = fmap4(nk1);
            st_sd<true >(qf , l0s, col4, nq0, nq1);
            st_sd<false>(kfx, l0s, col4, fk0, fk1);
            lk0 = fk0; lk1 = fk1; lv0 = nv0; lv1 = nv1;
        }
        __syncthreads();                        // barrier A (next chunk)
    }
}

extern "C" void kernel_launch(void* const* d_in, const int* in_sizes, int n_in,
                              void* d_out, int out_size, void* d_ws, size_t ws_size,
                              hipStream_t stream) {
    const float* q = (const float*)d_in[0];
    const float* k = (const float*)d_in[1];
    const float* v = (const float*)d_in[2];
    float* out = (float*)d_out;
    float* qkv = (float*)d_ws;                                      // 512 * 4096 fp32 = 8 MiB
    float* ksq = (float*)((char*)d_ws + (size_t)512*4096*4);        // 512 * 64 fp32 = 128 KiB
    kA<<<512, 256, 0, stream>>>(k, v, qkv, ksq);
    kM<<<256, 512, 0, stream>>>(q, k, v, qkv, ksq, out);
}